// Round 1
// baseline (104.378 us; speedup 1.0000x reference)
//
#include <hip/hip_runtime.h>

#define BB 8
#define NN 2048
#define IND 10
#define QK 32

// Kernel 1: q[b][n][qd] = sum_d s[b,n,d]*Wq[qd,d]; k likewise.
// k stored in ev-transposed layout: kt[b][ev=qd/4][n][qd%4] so kernel 2
// reads per-(ev) contiguous float4 runs across columns (perfect coalescing).
__global__ __launch_bounds__(256) void qk_kernel(
    const float* __restrict__ s,
    const float* __restrict__ Wq, const float* __restrict__ Wk,
    float* __restrict__ q_ws, float* __restrict__ kt_ws) {
  int t = blockIdx.x * 256 + threadIdx.x;      // 0 .. B*N*QK-1 (exact)
  int b  = t >> 16;                            // N*QK = 65536
  int n  = (t >> 5) & (NN - 1);
  int qd = t & 31;
  const float* srow = s + (size_t)(b * NN + n) * IND;
  float acq = 0.f, ack = 0.f;
#pragma unroll
  for (int d = 0; d < IND; ++d) {
    float sv = srow[d];
    acq = fmaf(sv, Wq[qd * IND + d], acq);
    ack = fmaf(sv, Wk[qd * IND + d], ack);
  }
  q_ws[(size_t)(b * NN + n) * QK + qd] = acq;
  kt_ws[((size_t)(b * 8 + (qd >> 2)) * NN + n) * 4 + (qd & 3)] = ack;
}

// Kernel 2: one block = one batch b, 8 consecutive rows.
// 256 threads; thread owns 8 consecutive cols (tid*8..tid*8+7) for all 8 rows.
// acc[8][8] fp32 in registers; q rows broadcast from LDS; k from L2 (2MB total,
// resident); G/out streamed coalesced as float4.
__global__ __launch_bounds__(256) void attn_kernel(
    const float* __restrict__ G,
    const float* __restrict__ q_ws, const float* __restrict__ kt_ws,
    float* __restrict__ out) {
  const int tid = threadIdx.x;
  const int b = blockIdx.y;
  const int r0 = blockIdx.x * 8;

  __shared__ float q_lds[8 * 32];
  __shared__ float red[4][8];

  {  // stage 8 rows of q (8*32 floats), coalesced
    int row = tid >> 5, e = tid & 31;
    q_lds[tid] = q_ws[((size_t)b * NN + r0 + row) * QK + e];
  }
  __syncthreads();

  float acc[8][8];
#pragma unroll
  for (int r = 0; r < 8; ++r)
#pragma unroll
    for (int j = 0; j < 8; ++j) acc[r][j] = 0.f;

  const float4* kt = (const float4*)kt_ws;  // [b][ev][n] of float4
  const int cbase = tid * 8;

#pragma unroll
  for (int ev = 0; ev < 8; ++ev) {
    float4 q4[8];
#pragma unroll
    for (int r = 0; r < 8; ++r)
      q4[r] = *(const float4*)&q_lds[r * 32 + ev * 4];  // broadcast read
    const float4* krow = kt + (size_t)(b * 8 + ev) * NN + cbase;
#pragma unroll
    for (int j = 0; j < 8; ++j) {
      float4 k4 = krow[j];
#pragma unroll
      for (int r = 0; r < 8; ++r) {
        acc[r][j] = fmaf(q4[r].x, k4.x, acc[r][j]);
        acc[r][j] = fmaf(q4[r].y, k4.y, acc[r][j]);
        acc[r][j] = fmaf(q4[r].z, k4.z, acc[r][j]);
        acc[r][j] = fmaf(q4[r].w, k4.w, acc[r][j]);
      }
    }
  }

  // v = logits^2 * G; per-thread partial row sums
  float rsum[8];
#pragma unroll
  for (int r = 0; r < 8; ++r) {
    const float* Grow = G + ((size_t)b * NN + r0 + r) * NN + cbase;
    float gg[8];
    *(float4*)&gg[0] = *(const float4*)&Grow[0];
    *(float4*)&gg[4] = *(const float4*)&Grow[4];
    float sum = 0.f;
#pragma unroll
    for (int j = 0; j < 8; ++j) {
      float v = acc[r][j];
      v = v * v * gg[j];
      acc[r][j] = v;
      sum += v;
    }
    rsum[r] = sum;
  }

  // 64-lane butterfly reduce, then 4-wave LDS reduce
#pragma unroll
  for (int r = 0; r < 8; ++r) {
    float v = rsum[r];
#pragma unroll
    for (int off = 32; off >= 1; off >>= 1) v += __shfl_xor(v, off, 64);
    rsum[r] = v;
  }
  const int wid = tid >> 6;
  if ((tid & 63) == 0) {
#pragma unroll
    for (int r = 0; r < 8; ++r) red[wid][r] = rsum[r];
  }
  __syncthreads();

  float inv[8];
#pragma unroll
  for (int r = 0; r < 8; ++r) {
    float total = red[0][r] + red[1][r] + red[2][r] + red[3][r];
    inv[r] = 1.0f / (total + 1e-6f);
  }

#pragma unroll
  for (int r = 0; r < 8; ++r) {
    float* orow = out + ((size_t)b * NN + r0 + r) * NN + cbase;
    float oo[8];
#pragma unroll
    for (int j = 0; j < 8; ++j) oo[j] = acc[r][j] * inv[r];
    *(float4*)&orow[0] = *(const float4*)&oo[0];
    *(float4*)&orow[4] = *(const float4*)&oo[4];
  }
}

extern "C" void kernel_launch(void* const* d_in, const int* in_sizes, int n_in,
                              void* d_out, int out_size, void* d_ws, size_t ws_size,
                              hipStream_t stream) {
  const float* s  = (const float*)d_in[0];
  const float* G  = (const float*)d_in[1];
  const float* Wq = (const float*)d_in[2];
  const float* Wk = (const float*)d_in[3];
  float* out = (float*)d_out;

  float* q_ws  = (float*)d_ws;                       // B*N*QK floats = 2 MB
  float* kt_ws = q_ws + (size_t)BB * NN * QK;        // another 2 MB

  qk_kernel<<<(BB * NN * QK) / 256, 256, 0, stream>>>(s, Wq, Wk, q_ws, kt_ws);

  dim3 grid(NN / 8, BB);
  attn_kernel<<<grid, 256, 0, stream>>>(G, q_ws, kt_ws, out);
}